// Round 3
// baseline (28818.723 us; speedup 1.0000x reference)
//
#include <hip/hip_runtime.h>
#include <math.h>

// Problem constants
#define EMBD 400
#define HIDD 300
#define KEYD 128
#define VALD 128
#define NVOC 33
#define TT 256
#define BB 256
#define SS 512
#define WIH_LD 528          // EMB+VAL
#define GDIM 1200           // 4*HID
#define KTOT 428            // ctx(128)+h(300)
#define NJT 75              // gates j-tiles (1200/16)
#define NKT 14              // gates k-tiles (448/32): kt0-3 ctx, kt4-13 h
#define NBLK 256

typedef unsigned short u16;
typedef short bf16x8 __attribute__((ext_vector_type(8)));
typedef float f32x4 __attribute__((ext_vector_type(4)));

__device__ __forceinline__ f32x4 mfma16(bf16x8 a, bf16x8 b, f32x4 c) {
    return __builtin_amdgcn_mfma_f32_16x16x32_bf16(a, b, c, 0, 0, 0);
}
__device__ __forceinline__ u16 f2bf(float x) {   // RNE, no NaN inputs
    unsigned int u = __float_as_uint(x);
    return (u16)((u + 0x7fffu + ((u >> 16) & 1u)) >> 16);
}
__device__ __forceinline__ float bf2f(u16 h) {
    return __uint_as_float(((unsigned int)h) << 16);
}
__device__ __forceinline__ void bf2term(float x, u16& hi, u16& lo) {
    hi = f2bf(x);
    lo = f2bf(x - bf2f(hi));
}
__device__ __forceinline__ float sigmoidf_(float x) {
    return 1.f / (1.f + __expf(-x));
}
__device__ __forceinline__ float tanh_f(float x) {
    float ax = fabsf(x);
    if (ax > 15.f) return x > 0.f ? 1.f : -1.f;
    float e = __expf(2.f * x);
    return (e - 1.f) / (e + 1.f);
}

// ---------------- Precompute: E2[v][j] = b_ih[j]+b_hh[j]+emb[v]·W_ih[j][:400]
__global__ __launch_bounds__(256) void p_e2(
    const float* __restrict__ emb, const float* __restrict__ Wih,
    const float* __restrict__ bih, const float* __restrict__ bhh,
    float* __restrict__ E2)
{
    __shared__ float es[EMBD];
    const int v = blockIdx.x;
    for (int i = threadIdx.x; i < EMBD; i += 256) es[i] = emb[v * EMBD + i];
    __syncthreads();
    for (int j = threadIdx.x; j < GDIM; j += 256) {
        const float* wr = &Wih[(size_t)j * WIH_LD];
        float s0 = 0.f, s1 = 0.f, s2 = 0.f, s3 = 0.f;
        for (int e = 0; e < EMBD; e += 4) {
            s0 += es[e]     * wr[e];
            s1 += es[e + 1] * wr[e + 1];
            s2 += es[e + 2] * wr[e + 2];
            s3 += es[e + 3] * wr[e + 3];
        }
        E2[v * GDIM + j] = bih[j] + bhh[j] + ((s0 + s1) + (s2 + s3));
    }
}

// ---------------- Precompute: Wtb -> MFMA B-fragment tiles; phi -> hi/lo tiles
// B-frag for 16x16x32: lane l holds B[k=(l>>4)*8+e][col=l&15], elem idx lane*8+e.
__global__ __launch_bounds__(256) void p_wt(
    const float* __restrict__ Wih, const float* __restrict__ Whh,
    const float* __restrict__ phi_w,
    u16* __restrict__ Wtbf, u16* __restrict__ phiH, u16* __restrict__ phiL)
{
    const int stride = gridDim.x * 256;
    const int tot1 = NJT * NKT * 512;
    for (int i = blockIdx.x * 256 + threadIdx.x; i < tot1; i += stride) {
        int tile = i >> 9, rem = i & 511;
        int lane = rem >> 3, e = rem & 7;
        int jt = tile / NKT, kt = tile - jt * NKT;
        int k = kt * 32 + ((lane >> 4) << 3) + e;
        int j = jt * 16 + (lane & 15);
        float v = 0.f;
        if (k < KEYD)      v = Wih[(size_t)j * WIH_LD + EMBD + k];
        else if (k < KTOT) v = Whh[(size_t)j * HIDD + (k - KEYD)];
        Wtbf[i] = f2bf(v);
    }
    const int tot2 = 8 * 10 * 512;   // qt x it tiles
    for (int i = blockIdx.x * 256 + threadIdx.x; i < tot2; i += stride) {
        int tile = i >> 9, rem = i & 511;
        int lane = rem >> 3, e = rem & 7;
        int qt = tile / 10, it = tile - qt * 10;
        int ii = it * 32 + ((lane >> 4) << 3) + e;
        int kc = qt * 16 + (lane & 15);
        float v = (ii < HIDD) ? phi_w[(size_t)kc * HIDD + ii] : 0.f;
        u16 h_, l_;
        bf2term(v, h_, l_);
        phiH[i] = h_; phiL[i] = l_;
    }
}

// ---------------- Precompute: K -> A-frag tiles [b][stile][kt]; V -> B-frag
// tiles [b][kt][vt]. A-frag: lane holds A[row=l&15][k=(l>>4)*8+e].
__global__ __launch_bounds__(1024) void p_kv(
    const float* __restrict__ keys, const float* __restrict__ values,
    u16* __restrict__ kfr, u16* __restrict__ vfr)
{
    size_t i = (size_t)blockIdx.x * 1024 + threadIdx.x;  // S*B*128 exactly
    int s = (int)(i >> 15);
    int r = (int)(i & 32767);
    int b = r >> 7, d = r & 127;
    {   // K: tile (stile=s>>4, kt=d>>5); row=s&15, k_local=d&31
        int lane = (s & 15) + (((d & 31) >> 3) << 4), e = d & 7;
        size_t dst = ((size_t)b << 16) + ((size_t)(((s >> 4) << 2) + (d >> 5)) << 9)
                   + (lane << 3) + e;
        kfr[dst] = f2bf(keys[i]);
    }
    {   // V: tile (kt=s>>5, vt=d>>4); col=d&15, k_local=s&31
        int sl = s & 31;
        int lane = (d & 15) + ((sl >> 3) << 4), e = sl & 7;
        size_t dst = ((size_t)b << 16) + ((size_t)(((s >> 5) << 3) + (d >> 4)) << 9)
                   + (lane << 3) + e;
        vfr[dst] = f2bf(values[i]);
    }
}

// ---------------- Whh chunk: gates k-tiles m0..m1 (m = gates_kt - 4)
template<int M0, int M1>
__device__ __forceinline__ void whh_chunk(
    const u16* __restrict__ Wtbf, int jt0, int njt, int ln,
    const bf16x8 (&ah)[10], const bf16x8 (&al)[10], f32x4 (&gacc)[10])
{
    #pragma unroll
    for (int r = 0; r < 10; ++r) if (r < njt) {
        const u16* wt = Wtbf + ((size_t)((jt0 + r) * NKT) << 9) + (ln << 3);
        #pragma unroll
        for (int m = M0; m < M1; ++m) {
            bf16x8 B = *reinterpret_cast<const bf16x8*>(wt + ((m + 4) << 9));
            gacc[r] = mfma16(ah[m], B, gacc[r]);
            gacc[r] = mfma16(al[m], B, gacc[r]);
        }
    }
}

// =====================================================================
__global__ void __launch_bounds__(512, 2) decoder_mf(
    const int* __restrict__ input,
    const u16* __restrict__ kfr, const u16* __restrict__ vfr,
    const u16* __restrict__ phiH, const u16* __restrict__ phiL,
    const float* __restrict__ phi_b, const float* __restrict__ h0,
    const float* __restrict__ c0, const float* __restrict__ projw,
    const float* __restrict__ projb, const float* __restrict__ E2,
    const u16* __restrict__ Wtbf, float* __restrict__ out)
{
    const int tid = threadIdx.x;
    const int b   = blockIdx.x;
    const int wv  = tid >> 6;       // wave 0..7
    const int ln  = tid & 63;
    const int l15 = ln & 15;
    const int lg  = ln >> 4;        // 0..3

    // gates j-tile ownership: wave0: 5 tiles (70..74); waves1-7: 10 each
    const int njt = (wv == 0) ? 5 : 10;
    const int jt0 = (wv == 0) ? 70 : (wv - 1) * 10;

    __shared__ float h_s[HIDD];
    __shared__ float c_s[HIDD];
    __shared__ float ctx2[2][VALD];                  // double-buffered ctx
    __shared__ __align__(16) u16 xin_hi[448];        // [ctx 0..127 | h 128..427 | pad]
    __shared__ __align__(16) u16 xin_lo[448];
    __shared__ __align__(16) float gl[GDIM];
    __shared__ __align__(16) float att[SS];
    __shared__ __align__(16) u16 att_hi[SS];
    __shared__ __align__(16) u16 att_lo[SS];
    __shared__ __align__(16) float q_s[KEYD];
    __shared__ int xv_s;

    const u16* kb = kfr + ((size_t)b << 16);
    const u16* vb = vfr + ((size_t)b << 16);

    // ---- init
    for (int j = tid; j < HIDD; j += 512) {
        float hv = h0[j];
        h_s[j] = hv;
        c_s[j] = c0[j];
        u16 hh, ll; bf2term(hv, hh, ll);
        xin_hi[128 + j] = hh; xin_lo[128 + j] = ll;
    }
    if (tid < 20) { xin_hi[KTOT + tid] = 0; xin_lo[KTOT + tid] = 0; }
    if (tid == 0) xv_s = input[b];
    __syncthreads();

    bf16x8 ah[10], al[10];
    f32x4 gacc[10];

    // ================= prologue: attend(h0) -> ctx(-1); then full gates ====
    // P1': build h A-frags + qpart
    #pragma unroll
    for (int m = 0; m < 10; ++m) {
        ah[m] = *reinterpret_cast<const bf16x8*>(&xin_hi[128 + m * 32 + lg * 8]);
        al[m] = *reinterpret_cast<const bf16x8*>(&xin_lo[128 + m * 32 + lg * 8]);
    }
    {
        f32x4 qa = {0.f, 0.f, 0.f, 0.f};
        const u16* ph = phiH + ((size_t)(wv * 10) << 9) + (ln << 3);
        const u16* pl = phiL + ((size_t)(wv * 10) << 9) + (ln << 3);
        #pragma unroll
        for (int it = 0; it < 10; ++it) {
            bf16x8 bh = *reinterpret_cast<const bf16x8*>(ph + (it << 9));
            bf16x8 bl = *reinterpret_cast<const bf16x8*>(pl + (it << 9));
            qa = mfma16(ah[it], bh, qa);
            qa = mfma16(al[it], bh, qa);
            qa = mfma16(ah[it], bl, qa);
        }
        if (ln < 16) q_s[wv * 16 + ln] = qa[0] + phi_b[wv * 16 + ln];
    }
    __syncthreads();

    #pragma unroll 1
    for (int t = -1; t < TT; ++t) {
        // =========== P2: energy (this step's q) ===========
        {
            bf16x8 qh[4], ql[4];
            #pragma unroll
            for (int kt = 0; kt < 4; ++kt) {
                const float* qs = &q_s[kt * 32 + lg * 8];
                bf16x8 h8, l8;
                #pragma unroll
                for (int e = 0; e < 8; ++e) {
                    u16 hh, ll; bf2term(qs[e], hh, ll);
                    h8[e] = (short)hh; l8[e] = (short)ll;
                }
                qh[kt] = h8; ql[kt] = l8;
            }
            #pragma unroll
            for (int st = 0; st < 4; ++st) {
                const int stile = wv * 4 + st;
                f32x4 ea = {0.f, 0.f, 0.f, 0.f};
                const u16* kt0p = kb + ((size_t)(stile << 2) << 9) + (ln << 3);
                #pragma unroll
                for (int kt = 0; kt < 4; ++kt) {
                    bf16x8 A = *reinterpret_cast<const bf16x8*>(kt0p + (kt << 9));
                    ea = mfma16(A, qh[kt], ea);
                    ea = mfma16(A, ql[kt], ea);
                }
                if (l15 == 0) {
                    #pragma unroll
                    for (int rg = 0; rg < 4; ++rg)
                        att[stile * 16 + lg * 4 + rg] = ea[rg];
                }
            }
        }
        if (t >= 0) whh_chunk<4, 7>(Wtbf, jt0, njt, ln, ah, al, gacc);
        __syncthreads();

        // =========== P3: softmax (wave0) || Whh tail + logits ===========
        if (wv == 0) {
            const float4* a4 = reinterpret_cast<const float4*>(att);
            float4 e0 = a4[ln * 2], e1 = a4[ln * 2 + 1];
            float m = fmaxf(fmaxf(fmaxf(e0.x, e0.y), fmaxf(e0.z, e0.w)),
                            fmaxf(fmaxf(e1.x, e1.y), fmaxf(e1.z, e1.w)));
            #pragma unroll
            for (int off = 32; off; off >>= 1) m = fmaxf(m, __shfl_xor(m, off));
            float p[8];
            p[0] = __expf(e0.x - m); p[1] = __expf(e0.y - m);
            p[2] = __expf(e0.z - m); p[3] = __expf(e0.w - m);
            p[4] = __expf(e1.x - m); p[5] = __expf(e1.y - m);
            p[6] = __expf(e1.z - m); p[7] = __expf(e1.w - m);
            float ss = ((p[0] + p[1]) + (p[2] + p[3]))
                     + ((p[4] + p[5]) + (p[6] + p[7]));
            #pragma unroll
            for (int off = 32; off; off >>= 1) ss += __shfl_xor(ss, off);
            const float inv = 1.f / ss;
            bf16x8 h8, l8;
            #pragma unroll
            for (int e = 0; e < 8; ++e) {
                u16 hh, ll; bf2term(p[e] * inv, hh, ll);
                h8[e] = (short)hh; l8[e] = (short)ll;
            }
            *reinterpret_cast<bf16x8*>(&att_hi[ln * 8]) = h8;
            *reinterpret_cast<bf16x8*>(&att_lo[ln * 8]) = l8;
        } else if (t >= 0) {
            whh_chunk<7, 10>(Wtbf, jt0, njt, ln, ah, al, gacc);
            if (tid >= 64 && tid < 196) {        // logits: 33 vocab x 4 lanes
                const int idx = tid - 64;
                const int v = idx >> 2, l = idx & 3;
                const float* pw = projw + (size_t)v * KTOT;
                const float* cr = ctx2[t & 1];
                float s = 0.f;
                #pragma unroll 4
                for (int k = l; k < KTOT; k += 4)
                    s += pw[k] * ((k < HIDD) ? h_s[k] : cr[k - HIDD]);
                s += __shfl_xor(s, 1);
                s += __shfl_xor(s, 2);
                if (l == 0)
                    out[((size_t)t * BB + b) * NVOC + v] = s + projb[v];
            }
        }
        __syncthreads();
        if (t == TT - 1) break;

        // =========== P4: ctx = att·V (wave w owns vt=w) + xv prefetch ======
        {
            f32x4 ca = {0.f, 0.f, 0.f, 0.f};
            const u16* vp = vb + ((size_t)wv << 9) + (ln << 3);
            #pragma unroll
            for (int kt = 0; kt < 16; ++kt) {
                bf16x8 aH = *reinterpret_cast<const bf16x8*>(&att_hi[kt * 32 + lg * 8]);
                bf16x8 aL = *reinterpret_cast<const bf16x8*>(&att_lo[kt * 32 + lg * 8]);
                bf16x8 B  = *reinterpret_cast<const bf16x8*>(vp + ((size_t)(kt << 3) << 9));
                ca = mfma16(aH, B, ca);
                ca = mfma16(aL, B, ca);
            }
            if (ln < 16) {
                const float cv = ca[0];
                ctx2[(t + 1) & 1][wv * 16 + ln] = cv;
                u16 hh, ll; bf2term(cv, hh, ll);
                xin_hi[wv * 16 + ln] = hh; xin_lo[wv * 16 + ln] = ll;
            }
            if (tid == 0 && t + 1 < TT) xv_s = input[(t + 1) * BB + b];
        }
        __syncthreads();

        // =========== P5: Wctx gates (kt 0..3) [+ full h-part if prologue] ==
        {
            bf16x8 ch[4], cl[4];
            #pragma unroll
            for (int m = 0; m < 4; ++m) {
                ch[m] = *reinterpret_cast<const bf16x8*>(&xin_hi[m * 32 + lg * 8]);
                cl[m] = *reinterpret_cast<const bf16x8*>(&xin_lo[m * 32 + lg * 8]);
            }
            if (t < 0) {
                // prologue: full gates (ctx + h) -> gl
                #pragma unroll
                for (int r = 0; r < 10; ++r) if (r < njt) {
                    const int jt = jt0 + r;
                    f32x4 acc = {0.f, 0.f, 0.f, 0.f};
                    const u16* wt = Wtbf + ((size_t)(jt * NKT) << 9) + (ln << 3);
                    #pragma unroll
                    for (int m = 0; m < 4; ++m) {
                        bf16x8 B = *reinterpret_cast<const bf16x8*>(wt + (m << 9));
                        acc = mfma16(ch[m], B, acc);
                        acc = mfma16(cl[m], B, acc);
                    }
                    #pragma unroll
                    for (int m = 0; m < 10; ++m) {
                        bf16x8 B = *reinterpret_cast<const bf16x8*>(wt + ((m + 4) << 9));
                        acc = mfma16(ah[m], B, acc);
                        acc = mfma16(al[m], B, acc);
                    }
                    if (ln < 16) gl[jt * 16 + ln] = acc[0];
                }
            } else {
                #pragma unroll
                for (int r = 0; r < 10; ++r) if (r < njt) {
                    const int jt = jt0 + r;
                    const u16* wt = Wtbf + ((size_t)(jt * NKT) << 9) + (ln << 3);
                    #pragma unroll
                    for (int m = 0; m < 4; ++m) {
                        bf16x8 B = *reinterpret_cast<const bf16x8*>(wt + (m << 9));
                        gacc[r] = mfma16(ch[m], B, gacc[r]);
                        gacc[r] = mfma16(cl[m], B, gacc[r]);
                    }
                    if (ln < 16) gl[jt * 16 + ln] = gacc[r][0];
                }
            }
        }
        __syncthreads();

        // =========== P0 (next step): cell update ===========
        if (tid < HIDD) {
            const int j = tid;
            const float* e2r = E2 + (size_t)xv_s * GDIM;
            float gi = gl[j]            + e2r[j];
            float gf = gl[HIDD + j]     + e2r[HIDD + j];
            float gg = gl[2 * HIDD + j] + e2r[2 * HIDD + j];
            float go = gl[3 * HIDD + j] + e2r[3 * HIDD + j];
            float ig = sigmoidf_(gi);
            float fg = sigmoidf_(gf);
            float gt = tanh_f(gg);
            float og = sigmoidf_(go);
            float cn = fg * c_s[j] + ig * gt;
            c_s[j] = cn;
            float hv = og * tanh_f(cn);
            h_s[j] = hv;
            u16 hh, ll; bf2term(hv, hh, ll);
            xin_hi[128 + j] = hh; xin_lo[128 + j] = ll;
        }
        __syncthreads();

        // =========== P1 (next step): h A-frags + qpart + Whh head ==========
        #pragma unroll
        for (int m = 0; m < 10; ++m) {
            ah[m] = *reinterpret_cast<const bf16x8*>(&xin_hi[128 + m * 32 + lg * 8]);
            al[m] = *reinterpret_cast<const bf16x8*>(&xin_lo[128 + m * 32 + lg * 8]);
        }
        {
            f32x4 qa = {0.f, 0.f, 0.f, 0.f};
            const u16* ph = phiH + ((size_t)(wv * 10) << 9) + (ln << 3);
            const u16* pl = phiL + ((size_t)(wv * 10) << 9) + (ln << 3);
            #pragma unroll
            for (int it = 0; it < 10; ++it) {
                bf16x8 bh = *reinterpret_cast<const bf16x8*>(ph + (it << 9));
                bf16x8 bl = *reinterpret_cast<const bf16x8*>(pl + (it << 9));
                qa = mfma16(ah[it], bh, qa);
                qa = mfma16(al[it], bh, qa);
                qa = mfma16(ah[it], bl, qa);
            }
            if (ln < 16) q_s[wv * 16 + ln] = qa[0] + phi_b[wv * 16 + ln];
        }
        #pragma unroll
        for (int r = 0; r < 10; ++r)
            gacc[r] = (f32x4){0.f, 0.f, 0.f, 0.f};
        whh_chunk<0, 4>(Wtbf, jt0, njt, ln, ah, al, gacc);
        __syncthreads();
    }
}

// =====================================================================
extern "C" void kernel_launch(void* const* d_in, const int* in_sizes, int n_in,
                              void* d_out, int out_size, void* d_ws, size_t ws_size,
                              hipStream_t stream)
{
    const int*   input     = (const int*)  d_in[0];
    const float* keys      = (const float*)d_in[1];
    const float* values    = (const float*)d_in[2];
    const float* embedding = (const float*)d_in[3];
    const float* phi_w     = (const float*)d_in[4];
    const float* phi_b     = (const float*)d_in[5];
    const float* h0        = (const float*)d_in[6];
    const float* c0        = (const float*)d_in[7];
    const float* W_ih      = (const float*)d_in[8];
    const float* b_ih      = (const float*)d_in[9];
    const float* W_hh      = (const float*)d_in[10];
    const float* b_hh      = (const float*)d_in[11];
    const float* proj_w    = (const float*)d_in[12];
    const float* proj_b    = (const float*)d_in[13];
    float* out = (float*)d_out;

    char* base = (char*)d_ws;
    size_t off = 0;
    auto alloc = [&](size_t bytes) {
        size_t o = off;
        off = (off + bytes + 255) & ~(size_t)255;
        return o;
    };
    size_t oE2   = alloc((size_t)NVOC * GDIM * 4);        // 158 KB
    size_t oPhiH = alloc((size_t)8 * 10 * 512 * 2);       // 80 KB
    size_t oPhiL = alloc((size_t)8 * 10 * 512 * 2);       // 80 KB
    size_t oWtb  = alloc((size_t)NJT * NKT * 512 * 2);    // 1.05 MB
    size_t oKfr  = alloc((size_t)BB * 65536 * 2);         // 33.6 MB
    size_t oVfr  = alloc((size_t)BB * 65536 * 2);         // 33.6 MB
    (void)off;

    float* E2  = (float*)(base + oE2);
    u16* phiH  = (u16*)(base + oPhiH);
    u16* phiL  = (u16*)(base + oPhiL);
    u16* Wtbf  = (u16*)(base + oWtb);
    u16* kfr   = (u16*)(base + oKfr);
    u16* vfr   = (u16*)(base + oVfr);

    p_e2<<<NVOC, 256, 0, stream>>>(embedding, W_ih, b_ih, b_hh, E2);
    p_wt<<<2048, 256, 0, stream>>>(W_ih, W_hh, phi_w, Wtbf, phiH, phiL);
    p_kv<<<(SS * BB * KEYD) / 1024, 1024, 0, stream>>>(keys, values, kfr, vfr);

    decoder_mf<<<NBLK, 512, 0, stream>>>(
        input, kfr, vfr, phiH, phiL, phi_b, h0, c0,
        proj_w, proj_b, E2, Wtbf, out);
}

// Round 4
// 9912.041 us; speedup vs baseline: 2.9074x; 2.9074x over previous
//
#include <hip/hip_runtime.h>
#include <math.h>

// Problem constants
#define EMBD 400
#define HIDD 300
#define KEYD 128
#define VALD 128
#define NVOC 33
#define TT 256
#define BB 256
#define SS 512
#define WIH_LD 528          // EMB+VAL
#define GDIM 1200           // 4*HID
#define KTOT 428            // ctx(128)+h(300)
#define KPAD 432
#define NBLK 256            // one block per batch row -> all 256 CUs

typedef unsigned int u32x4 __attribute__((ext_vector_type(4)));
typedef unsigned int u32x2 __attribute__((ext_vector_type(2)));

__device__ __forceinline__ float bflo(unsigned int u) {
    return __uint_as_float(u << 16);
}
__device__ __forceinline__ float bfhi(unsigned int u) {
    return __uint_as_float(u & 0xffff0000u);
}
__device__ __forceinline__ unsigned short f2bf(float x) {   // RNE, no NaN inputs
    unsigned int u = __float_as_uint(x);
    return (unsigned short)((u + 0x7fffu + ((u >> 16) & 1u)) >> 16);
}
__device__ __forceinline__ float sigmoidf_(float x) {
    return 1.f / (1.f + __expf(-x));
}
__device__ __forceinline__ float tanh_f(float x) {
    float ax = fabsf(x);
    if (ax > 15.f) return x > 0.f ? 1.f : -1.f;
    float e = __expf(2.f * x);
    return (e - 1.f) / (e + 1.f);
}
__device__ __forceinline__ float4 add4(float4 a, float4 b) {
    return make_float4(a.x + b.x, a.y + b.y, a.z + b.z, a.w + b.w);
}

// ---- A-wave flag sync: only waves 0..3 participate; target = 4*generation.
__device__ __forceinline__ void a_sync(int* actr, int target) {
    asm volatile("s_waitcnt lgkmcnt(0)" ::: "memory");
    if ((threadIdx.x & 63) == 0) atomicAdd(actr, 1);
    while (__hip_atomic_load(actr, __ATOMIC_ACQUIRE,
                             __HIP_MEMORY_SCOPE_WORKGROUP) < target)
        __builtin_amdgcn_s_sleep(1);
}

// ---------------- Precompute: E2[v][j] = b_ih[j]+b_hh[j]+emb[v]·W_ih[j][:400]
__global__ __launch_bounds__(256) void p_e2(
    const float* __restrict__ emb, const float* __restrict__ Wih,
    const float* __restrict__ bih, const float* __restrict__ bhh,
    float* __restrict__ E2)
{
    __shared__ float es[EMBD];
    const int v = blockIdx.x;
    for (int i = threadIdx.x; i < EMBD; i += 256) es[i] = emb[v * EMBD + i];
    __syncthreads();
    for (int j = threadIdx.x; j < GDIM; j += 256) {
        const float* wr = &Wih[(size_t)j * WIH_LD];
        float s0 = 0.f, s1 = 0.f, s2 = 0.f, s3 = 0.f;
        for (int e = 0; e < EMBD; e += 4) {
            s0 += es[e]     * wr[e];
            s1 += es[e + 1] * wr[e + 1];
            s2 += es[e + 2] * wr[e + 2];
            s3 += es[e + 3] * wr[e + 3];
        }
        E2[v * GDIM + j] = bih[j] + bhh[j] + ((s0 + s1) + (s2 + s3));
    }
}

// ---------------- Precompute: Wtb (bf16, [k][j] fused) + phi_wT (f32 [i][k])
__global__ __launch_bounds__(256) void p_wt(
    const float* __restrict__ Wih, const float* __restrict__ Whh,
    const float* __restrict__ phi_w,
    unsigned short* __restrict__ Wtb, float* __restrict__ phi_wT)
{
    const int stride = gridDim.x * 256;
    for (int i = blockIdx.x * 256 + threadIdx.x; i < KPAD * GDIM; i += stride) {
        int k = i / GDIM, j = i - k * GDIM;
        float v = 0.f;
        if (k < KEYD)      v = Wih[(size_t)j * WIH_LD + EMBD + k];
        else if (k < KTOT) v = Whh[(size_t)j * HIDD + (k - KEYD)];
        Wtb[i] = f2bf(v);
    }
    for (int i = blockIdx.x * 256 + threadIdx.x; i < KEYD * HIDD; i += stride) {
        int k = i / HIDD, ii = i - k * HIDD;   // phi_w[k][ii]
        phi_wT[ii * KEYD + k] = phi_w[i];
    }
}

// ---------------- Precompute: KV -> bf16, transposed to [b][s][dim]
__global__ __launch_bounds__(1024) void p_kv(
    const float* __restrict__ keys, const float* __restrict__ values,
    unsigned short* __restrict__ kbf, unsigned short* __restrict__ vbf)
{
    size_t i = (size_t)blockIdx.x * 1024 + threadIdx.x;  // S*B*K total exactly
    int s = (int)(i >> 15);
    int r = (int)(i & 32767);
    int b = r >> 7, k = r & 127;
    size_t d = (((size_t)b * SS + s) << 7) + k;
    kbf[d] = f2bf(keys[i]);
    vbf[d] = f2bf(values[i]);
}

// ---------------- j-oct GEMM slice: 8 j's per thread, k range [k0,k0+NK)
template<int NK>
__device__ __forceinline__ void oct_accum(
    const unsigned short* __restrict__ Wtb, const float* __restrict__ xin,
    int o, int k0, float* a)
{
    const unsigned short* wp = Wtb + (size_t)k0 * GDIM + o * 8;
    #pragma unroll 5
    for (int i = 0; i < NK; ++i) {
        float x = xin[k0 + i];
        u32x4 w = *reinterpret_cast<const u32x4*>(wp + (size_t)i * GDIM);
        a[0] += x * bflo(w.x); a[1] += x * bfhi(w.x);
        a[2] += x * bflo(w.y); a[3] += x * bfhi(w.y);
        a[4] += x * bflo(w.z); a[5] += x * bfhi(w.z);
        a[6] += x * bflo(w.w); a[7] += x * bfhi(w.w);
    }
}

// =====================================================================
// Producer-consumer persistent block: waves 0-3 = attend chain (flag-synced),
// waves 4-15 = gates Whh stream + logits, no shared barriers inside phase 2.
__global__ void __launch_bounds__(1024, 4) decoder_pc(
    const int* __restrict__ input,
    const unsigned short* __restrict__ kbf, const unsigned short* __restrict__ vbf,
    const float* __restrict__ phi_wT, const float* __restrict__ phi_b,
    const float* __restrict__ h0, const float* __restrict__ c0,
    const float* __restrict__ projw, const float* __restrict__ projb,
    const float* __restrict__ E2, const unsigned short* __restrict__ Wtb,
    float* __restrict__ out)
{
    const int tid = threadIdx.x;
    const int b = blockIdx.x;

    __shared__ float h_s[HIDD];
    __shared__ float c_s[HIDD];
    __shared__ float ctx2[2][VALD];                  // ctx(t) in ctx2[t&1]
    __shared__ __align__(16) float xin[KPAD];        // [ctx 0..127 | h 128..427]
    __shared__ __align__(16) float gl4[4][GDIM];     // gates(t+1) partials, 19.2 KB
    __shared__ __align__(16) float att[SS];
    __shared__ __align__(16) float qp[2][KEYD];
    __shared__ __align__(16) float cpart[8][VALD];
    __shared__ __align__(16) float pb_s[KEYD];
    __shared__ int xv_s;
    __shared__ int actr;

    // ---- init
    for (int j = tid; j < HIDD; j += 1024) {
        float hv = h0[j];
        h_s[j] = hv;
        c_s[j] = c0[j];
        xin[VALD + j] = hv;
    }
    if (tid < KEYD) pb_s[tid] = phi_b[tid];
    if (tid < KPAD - KTOT) xin[KTOT + tid] = 0.f;
    if (tid == 0) { xv_s = input[b]; actr = 0; }
    __syncthreads();

    int asyn = 0;

    #pragma unroll 1
    for (int t = -1; t < TT; ++t) {
        // ---------- P0: cell(t): gates(t) = gl4 sums + E2[x_t] ----------
        if (t >= 0 && tid < HIDD) {
            const int j = tid;
            const float* e2r = E2 + (size_t)xv_s * GDIM;
            float s0 = gl4[0][j] + gl4[1][j] + gl4[2][j] + gl4[3][j] + e2r[j];
            float s1 = gl4[0][HIDD + j] + gl4[1][HIDD + j]
                     + gl4[2][HIDD + j] + gl4[3][HIDD + j] + e2r[HIDD + j];
            float s2 = gl4[0][2 * HIDD + j] + gl4[1][2 * HIDD + j]
                     + gl4[2][2 * HIDD + j] + gl4[3][2 * HIDD + j]
                     + e2r[2 * HIDD + j];
            float s3 = gl4[0][3 * HIDD + j] + gl4[1][3 * HIDD + j]
                     + gl4[2][3 * HIDD + j] + gl4[3][3 * HIDD + j]
                     + e2r[3 * HIDD + j];
            float ig = sigmoidf_(s0);
            float fg = sigmoidf_(s1);
            float gt = tanh_f(s2);
            float og = sigmoidf_(s3);
            float cn = fg * c_s[j] + ig * gt;
            c_s[j] = cn;
            float hv = og * tanh_f(cn);
            h_s[j] = hv;
            xin[VALD + j] = hv;
        }
        __syncthreads();

        // ---------- phase 2: A-chain || G-stream ----------
        if (tid < 256) {
            // ======== A side: attend(h(t)) -> ctx(t), flag-synced ========
            if (t < TT - 1) {
                // qpart: q[k] partials over 2 i-halves
                {
                    const int k = tid & 127, half = tid >> 7;
                    const int i0 = half * 150;
                    float acc = 0.f;
                    #pragma unroll 10
                    for (int i = i0; i < i0 + 150; ++i)
                        acc += h_s[i] * phi_wT[i * KEYD + k];
                    qp[half][k] = acc;
                }
                asyn += 4; a_sync(&actr, asyn);
                // energy: 16 lanes x 16 s-groups, fold q on the fly
                {
                    const int l16 = tid & 15, sg = tid >> 4;
                    const int ia = l16 * 2, ib = ia + 1;
                    const float4* pb4 = reinterpret_cast<const float4*>(pb_s);
                    const float4* q0 = reinterpret_cast<const float4*>(qp[0]);
                    const float4* q1 = reinterpret_cast<const float4*>(qp[1]);
                    const float4 qa = add4(pb4[ia], add4(q0[ia], q1[ia]));
                    const float4 qb = add4(pb4[ib], add4(q0[ib], q1[ib]));
                    const unsigned short* krow = kbf + ((size_t)b * SS) * KEYD;
                    #pragma unroll 4
                    for (int p = 0; p < 32; ++p) {
                        int s = p * 16 + sg;
                        const u32x4* kp = reinterpret_cast<const u32x4*>(
                            krow + (size_t)s * KEYD);
                        u32x4 w = __builtin_nontemporal_load(kp + l16);
                        float e = bflo(w.x) * qa.x + bfhi(w.x) * qa.y
                                + bflo(w.y) * qa.z + bfhi(w.y) * qa.w
                                + bflo(w.z) * qb.x + bfhi(w.z) * qb.y
                                + bflo(w.w) * qb.z + bfhi(w.w) * qb.w;
                        e += __shfl_xor(e, 1);
                        e += __shfl_xor(e, 2);
                        e += __shfl_xor(e, 4);
                        e += __shfl_xor(e, 8);
                        if (l16 == 0) att[s] = e;
                    }
                }
                asyn += 4; a_sync(&actr, asyn);
                // softmax: wave 0 solo, 8 energies per lane
                if (tid < 64) {
                    float4* a4 = reinterpret_cast<float4*>(att);
                    float4 e0 = a4[tid * 2], e1 = a4[tid * 2 + 1];
                    float m = fmaxf(fmaxf(fmaxf(e0.x, e0.y), fmaxf(e0.z, e0.w)),
                                    fmaxf(fmaxf(e1.x, e1.y), fmaxf(e1.z, e1.w)));
                    #pragma unroll
                    for (int off = 32; off; off >>= 1)
                        m = fmaxf(m, __shfl_xor(m, off));
                    float p0 = __expf(e0.x - m), p1 = __expf(e0.y - m);
                    float p2 = __expf(e0.z - m), p3 = __expf(e0.w - m);
                    float p4 = __expf(e1.x - m), p5 = __expf(e1.y - m);
                    float p6 = __expf(e1.z - m), p7 = __expf(e1.w - m);
                    float ss = ((p0 + p1) + (p2 + p3)) + ((p4 + p5) + (p6 + p7));
                    #pragma unroll
                    for (int off = 32; off; off >>= 1)
                        ss += __shfl_xor(ss, off);
                    float inv = 1.f / ss;
                    a4[tid * 2]     = make_float4(p0 * inv, p1 * inv, p2 * inv, p3 * inv);
                    a4[tid * 2 + 1] = make_float4(p4 * inv, p5 * inv, p6 * inv, p7 * inv);
                }
                asyn += 4; a_sync(&actr, asyn);
                // PV: 32 v-lanes x 8 s-groups of 64
                {
                    const int v4 = tid & 31, sg = tid >> 5;
                    float4 a = make_float4(0.f, 0.f, 0.f, 0.f);
                    const unsigned short* vrow = vbf + ((size_t)b * SS) * VALD;
                    #pragma unroll 4
                    for (int i = 0; i < 64; ++i) {
                        int s = sg * 64 + i;
                        const u32x2* vp = reinterpret_cast<const u32x2*>(
                            vrow + (size_t)s * VALD);
                        u32x2 w = __builtin_nontemporal_load(vp + v4);
                        float wt = att[s];
                        a.x += wt * bflo(w.x); a.y += wt * bfhi(w.x);
                        a.z += wt * bflo(w.y); a.w += wt * bfhi(w.y);
                    }
                    *reinterpret_cast<float4*>(&cpart[sg][v4 * 4]) = a;
                }
                asyn += 4; a_sync(&actr, asyn);
                if (tid < VALD) {
                    float s = 0.f;
                    #pragma unroll
                    for (int g = 0; g < 8; ++g) s += cpart[g][tid];
                    ctx2[t & 1][tid] = s;
                    xin[tid] = s;
                }
            }
        } else {
            const int g = tid - 256;   // 0..767
            if (g < 600) {
                // ======== G side: Whh·h(t) -> gl4 (write) ========
                if (t < TT - 1) {
                    const int c = g / 150, o = g - c * 150;
                    float a[8] = {0.f, 0.f, 0.f, 0.f, 0.f, 0.f, 0.f, 0.f};
                    oct_accum<75>(Wtb, xin, o, VALD + c * 75, a);
                    *reinterpret_cast<float4*>(&gl4[c][o * 8]) =
                        make_float4(a[0], a[1], a[2], a[3]);
                    *reinterpret_cast<float4*>(&gl4[c][o * 8 + 4]) =
                        make_float4(a[4], a[5], a[6], a[7]);
                }
            } else if (g < 732) {
                // ======== logits(t) from h(t), ctx(t-1) ========
                if (t >= 0) {
                    const int idx = g - 600;
                    const int v = idx >> 2, l = idx & 3;
                    const float* pw = projw + (size_t)v * KTOT;
                    const float* cr = ctx2[(t + 1) & 1];
                    float s = 0.f;
                    #pragma unroll 4
                    for (int k = l; k < KTOT; k += 4)
                        s += pw[k] * ((k < HIDD) ? h_s[k] : cr[k - HIDD]);
                    s += __shfl_xor(s, 1);
                    s += __shfl_xor(s, 2);
                    if (l == 0)
                        out[((size_t)t * BB + b) * NVOC + v] = s + projb[v];
                }
            } else if (g == 732) {
                if (t + 1 < TT) xv_s = input[(t + 1) * BB + b];
            }
        }
        __syncthreads();

        // ---------- phase Y: Wctx·ctx(t) adds into gl4 ----------
        if (t < TT - 1) {
            if (tid < 600) {
                const int c = tid / 150, o = tid - c * 150;
                float a[8] = {0.f, 0.f, 0.f, 0.f, 0.f, 0.f, 0.f, 0.f};
                oct_accum<32>(Wtb, xin, o, c * 32, a);
                float4 p0 = *reinterpret_cast<const float4*>(&gl4[c][o * 8]);
                float4 p1 = *reinterpret_cast<const float4*>(&gl4[c][o * 8 + 4]);
                p0.x += a[0]; p0.y += a[1]; p0.z += a[2]; p0.w += a[3];
                p1.x += a[4]; p1.y += a[5]; p1.z += a[6]; p1.w += a[7];
                *reinterpret_cast<float4*>(&gl4[c][o * 8]) = p0;
                *reinterpret_cast<float4*>(&gl4[c][o * 8 + 4]) = p1;
            }
            __syncthreads();
        }
    }
}

// =====================================================================
extern "C" void kernel_launch(void* const* d_in, const int* in_sizes, int n_in,
                              void* d_out, int out_size, void* d_ws, size_t ws_size,
                              hipStream_t stream)
{
    const int*   input     = (const int*)  d_in[0];
    const float* keys      = (const float*)d_in[1];
    const float* values    = (const float*)d_in[2];
    const float* embedding = (const float*)d_in[3];
    const float* phi_w     = (const float*)d_in[4];
    const float* phi_b     = (const float*)d_in[5];
    const float* h0        = (const float*)d_in[6];
    const float* c0        = (const float*)d_in[7];
    const float* W_ih      = (const float*)d_in[8];
    const float* b_ih      = (const float*)d_in[9];
    const float* W_hh      = (const float*)d_in[10];
    const float* b_hh      = (const float*)d_in[11];
    const float* proj_w    = (const float*)d_in[12];
    const float* proj_b    = (const float*)d_in[13];
    float* out = (float*)d_out;

    char* base = (char*)d_ws;
    size_t off = 0;
    auto alloc = [&](size_t bytes) {
        size_t o = off;
        off = (off + bytes + 255) & ~(size_t)255;
        return o;
    };
    size_t oE2   = alloc((size_t)NVOC * GDIM * 4);       // 158 KB
    size_t oPhi  = alloc((size_t)HIDD * KEYD * 4);       // 154 KB
    size_t oWtb  = alloc((size_t)KPAD * GDIM * 2);       // 1.04 MB
    size_t oKbf  = alloc((size_t)SS * BB * KEYD * 2);    // 33.6 MB
    size_t oVbf  = alloc((size_t)SS * BB * VALD * 2);    // 33.6 MB
    (void)off;

    float* E2 = (float*)(base + oE2);
    float* phi_wT = (float*)(base + oPhi);
    unsigned short* Wtb = (unsigned short*)(base + oWtb);
    unsigned short* kbf = (unsigned short*)(base + oKbf);
    unsigned short* vbf = (unsigned short*)(base + oVbf);

    p_e2<<<NVOC, 256, 0, stream>>>(embedding, W_ih, b_ih, b_hh, E2);
    p_wt<<<2048, 256, 0, stream>>>(W_ih, W_hh, phi_w, Wtb, phi_wT);
    p_kv<<<(SS * BB * KEYD) / 1024, 1024, 0, stream>>>(keys, values, kbf, vbf);

    decoder_pc<<<NBLK, 1024, 0, stream>>>(
        input, kbf, vbf, phi_wT, phi_b, h0, c0,
        proj_w, proj_b, E2, Wtb, out);
}